// Round 1
// baseline (554.560 us; speedup 1.0000x reference)
//
#include <hip/hip_runtime.h>

#define T_LEN 200
#define E_DIM 64
#define H1_DIM 80
#define H2_DIM 40
#define T_PAD 208   // 13 tiles of 16
#define K2_PAD 96   // H1 K-dim padded to 3*32
#define N2_PAD 48   // H2 cols padded to 3*16

typedef float f32x4 __attribute__((ext_vector_type(4)));
typedef short bf16x8 __attribute__((ext_vector_type(8)));

// ---- LDS layout (bytes) ----
#define OFF_KH 0
#define SZ_KH (T_PAD * K2_PAD * 2)            // 39936: union{ K[208][64]bf16, H1[208][96]bf16 }
#define OFF_MT (OFF_KH + SZ_KH)               // 39936
#define SZ_MT (H1_DIM * E_DIM * 2)            // 10240: Mt[j=80][e=64] bf16 (transposed)
#define OFF_W2T (OFF_MT + SZ_MT)              // 50176
#define SZ_W2T (N2_PAD * K2_PAD * 2)          // 9216: W2t[n=48][k=96] bf16
#define OFF_B1 (OFF_W2T + SZ_W2T)             // 59392
#define SZ_B1 (H1_DIM * 4)
#define OFF_B2 (OFF_B1 + SZ_B1)               // 59712
#define SZ_B2 (N2_PAD * 4)
#define OFF_WD (OFF_B2 + SZ_B2)               // 59904
#define SZ_WD (N2_PAD * 4)
#define OFF_Q  (OFF_WD + SZ_WD)               // 60096
#define SZ_Q (E_DIM * 4)
#define OFF_SC (OFF_Q + SZ_Q)                 // 60352
#define SZ_SC (T_PAD * 4)
#define OFF_PP (OFF_SC + SZ_SC)               // 61184
#define SZ_PP (4 * 64 * 4)
#define SMEM_TOTAL (OFF_PP + SZ_PP)           // 62208 < 64KB

static __device__ inline unsigned short f2bf(float x) {
  unsigned u = __builtin_bit_cast(unsigned, x);
  return (unsigned short)((u + 0x7fffu + ((u >> 16) & 1u)) >> 16);
}
static __device__ inline float sigm(float x) {
  return __builtin_amdgcn_rcpf(1.f + __expf(-x));
}

__global__ __launch_bounds__(256, 2)
void din_kernel(const float* __restrict__ query,
                const float* __restrict__ keys,
                const int* __restrict__ keys_length,
                const float* __restrict__ W1, const float* __restrict__ b1,
                const float* __restrict__ W2, const float* __restrict__ b2,
                const float* __restrict__ Wd, const float* __restrict__ bd,
                float* __restrict__ out) {
  __shared__ __align__(16) unsigned char smem[SMEM_TOTAL];
  unsigned short* KH  = (unsigned short*)(smem + OFF_KH);
  unsigned short* MT  = (unsigned short*)(smem + OFF_MT);
  unsigned short* W2T = (unsigned short*)(smem + OFF_W2T);
  float* BIAS1 = (float*)(smem + OFF_B1);
  float* B2P   = (float*)(smem + OFF_B2);
  float* WDP   = (float*)(smem + OFF_WD);
  float* QS    = (float*)(smem + OFF_Q);
  float* SC    = (float*)(smem + OFF_SC);
  float* PP    = (float*)(smem + OFF_PP);

  const int tid  = threadIdx.x;
  const int b    = blockIdx.x;
  const int lane = tid & 63;
  const int wv   = tid >> 6;   // wave 0..3
  const int qq   = lane >> 4;  // quad 0..3
  const int cc   = lane & 15;  // col 0..15

  const float* keyb = keys + (size_t)b * (T_LEN * E_DIM);

  // ---------- phase 0: stage q, keys->bf16, W2t, b2/Wd pads ----------
  if (tid < E_DIM) QS[tid] = query[b * E_DIM + tid];
  if (tid < N2_PAD) {
    B2P[tid] = (tid < H2_DIM) ? b2[tid] : 0.f;
    WDP[tid] = (tid < H2_DIM) ? Wd[tid] : 0.f;
  }
  // keys[b]: 200*64 f32 -> bf16 LDS rows [208][64] (pad rows zeroed)
  #pragma unroll
  for (int it = 0; it < 13; ++it) {
    int f = (it * 256 + tid) * 4;
    if (f < T_LEN * E_DIM) {
      const float4 v = *(const float4*)(keyb + f);
      unsigned p0 = ((unsigned)f2bf(v.y) << 16) | f2bf(v.x);
      unsigned p1 = ((unsigned)f2bf(v.w) << 16) | f2bf(v.z);
      *(uint2*)(KH + f) = make_uint2(p0, p1);
    } else if (f < T_PAD * E_DIM) {
      *(uint2*)(KH + f) = make_uint2(0u, 0u);
    }
  }
  // W2t[n][k] = W2[k][n] (bf16, zero-padded to 48x96)
  for (int idx = tid; idx < N2_PAD * K2_PAD; idx += 256) {
    int n = idx / K2_PAD, k = idx % K2_PAD;
    float v = (n < H2_DIM && k < H1_DIM) ? W2[k * H2_DIM + n] : 0.f;
    W2T[idx] = f2bf(v);
  }
  __syncthreads();

  // ---------- phase 1: per-b folded matrix Mt and bias1 ----------
  // M[e][j] = W1[64+e][j] - W1[128+e][j] + q[e]*W1[192+e][j]; stored transposed Mt[j][e]
  for (int idx = tid; idx < H1_DIM * E_DIM; idx += 256) {
    int j = idx >> 6;   // /64
    int e = idx & 63;
    float v = W1[(E_DIM + e) * H1_DIM + j] - W1[(2 * E_DIM + e) * H1_DIM + j]
            + QS[e] * W1[(3 * E_DIM + e) * H1_DIM + j];
    MT[idx] = f2bf(v);
  }
  if (tid < H1_DIM) {
    float s = b1[tid];
    for (int e = 0; e < E_DIM; ++e)
      s += QS[e] * (W1[e * H1_DIM + tid] + W1[(2 * E_DIM + e) * H1_DIM + tid]);
    BIAS1[tid] = s;
  }
  __syncthreads();

  // ---------- GEMM1: C1[208][80] = K[208][64] @ M[64][80] + bias ----------
  bf16x8 bfr[5][2];
  float bia[5];
  #pragma unroll
  for (int nt = 0; nt < 5; ++nt) {
    bia[nt] = BIAS1[nt * 16 + cc];
    #pragma unroll
    for (int ks = 0; ks < 2; ++ks)
      bfr[nt][ks] = *(const bf16x8*)(MT + (nt * 16 + cc) * E_DIM + ks * 32 + qq * 8);
  }
  f32x4 acc[4][5];
  #pragma unroll
  for (int ti = 0; ti < 4; ++ti) {
    const int tt = wv + ti * 4;
    if (tt < 13) {
      bf16x8 a0 = *(const bf16x8*)(KH + (tt * 16 + cc) * E_DIM + qq * 8);
      bf16x8 a1 = *(const bf16x8*)(KH + (tt * 16 + cc) * E_DIM + 32 + qq * 8);
      #pragma unroll
      for (int nt = 0; nt < 5; ++nt) {
        f32x4 a = {bia[nt], bia[nt], bia[nt], bia[nt]};
        a = __builtin_amdgcn_mfma_f32_16x16x32_bf16(a0, bfr[nt][0], a, 0, 0, 0);
        a = __builtin_amdgcn_mfma_f32_16x16x32_bf16(a1, bfr[nt][1], a, 0, 0, 0);
        acc[ti][nt] = a;
      }
    }
  }
  __syncthreads();  // all waves done reading K region before H1 overwrites it

  // epilogue: sigmoid -> H1[208][96] bf16 (cols 80..95 zeroed)
  unsigned short* H1 = KH;
  #pragma unroll
  for (int ti = 0; ti < 4; ++ti) {
    const int tt = wv + ti * 4;
    if (tt < 13) {
      #pragma unroll
      for (int nt = 0; nt < 5; ++nt)
        #pragma unroll
        for (int r = 0; r < 4; ++r)
          H1[(tt * 16 + qq * 4 + r) * K2_PAD + nt * 16 + cc] = f2bf(sigm(acc[ti][nt][r]));
      #pragma unroll
      for (int r = 0; r < 4; ++r)
        H1[(tt * 16 + qq * 4 + r) * K2_PAD + H1_DIM + cc] = 0;
    }
  }
  __syncthreads();

  // ---------- GEMM2: H2[208][48] = H1[208][96] @ W2p[96][48] + b2; fused score ----------
  bf16x8 bfr2[3][3];
  float b2c[3], wdl[3];
  #pragma unroll
  for (int nt = 0; nt < 3; ++nt) {
    b2c[nt] = B2P[nt * 16 + cc];
    wdl[nt] = WDP[nt * 16 + cc];
    #pragma unroll
    for (int ks = 0; ks < 3; ++ks)
      bfr2[nt][ks] = *(const bf16x8*)(W2T + (nt * 16 + cc) * K2_PAD + ks * 32 + qq * 8);
  }
  const float bdv = bd[0];
  const int len = keys_length[b];
  #pragma unroll
  for (int ti = 0; ti < 4; ++ti) {
    const int tt = wv + ti * 4;
    if (tt < 13) {
      bf16x8 a0 = *(const bf16x8*)(H1 + (tt * 16 + cc) * K2_PAD + qq * 8);
      bf16x8 a1 = *(const bf16x8*)(H1 + (tt * 16 + cc) * K2_PAD + 32 + qq * 8);
      bf16x8 a2 = *(const bf16x8*)(H1 + (tt * 16 + cc) * K2_PAD + 64 + qq * 8);
      float vr[4] = {0.f, 0.f, 0.f, 0.f};
      #pragma unroll
      for (int nt = 0; nt < 3; ++nt) {
        f32x4 ac = {b2c[nt], b2c[nt], b2c[nt], b2c[nt]};
        ac = __builtin_amdgcn_mfma_f32_16x16x32_bf16(a0, bfr2[nt][0], ac, 0, 0, 0);
        ac = __builtin_amdgcn_mfma_f32_16x16x32_bf16(a1, bfr2[nt][1], ac, 0, 0, 0);
        ac = __builtin_amdgcn_mfma_f32_16x16x32_bf16(a2, bfr2[nt][2], ac, 0, 0, 0);
        #pragma unroll
        for (int r = 0; r < 4; ++r)
          vr[r] += sigm(ac[r]) * wdl[nt];
      }
      // reduce over 16 lanes (cols), write masked score
      #pragma unroll
      for (int r = 0; r < 4; ++r) {
        float v = vr[r];
        v += __shfl_xor(v, 1);
        v += __shfl_xor(v, 2);
        v += __shfl_xor(v, 4);
        v += __shfl_xor(v, 8);
        if (cc == 0) {
          int t = tt * 16 + qq * 4 + r;
          SC[t] = (t < len) ? (bdv + v) : 0.f;
        }
      }
    }
  }
  __syncthreads();

  // ---------- pooling: out[b][e] = sum_t SC[t] * keys[b][t][e] (f32) ----------
  float accp = 0.f;
  for (int t = wv; t < T_LEN; t += 4)
    accp += SC[t] * keyb[t * E_DIM + lane];
  PP[wv * 64 + lane] = accp;
  __syncthreads();
  if (tid < E_DIM)
    out[(size_t)b * E_DIM + tid] = PP[tid] + PP[64 + tid] + PP[128 + tid] + PP[192 + tid];
}

extern "C" void kernel_launch(void* const* d_in, const int* in_sizes, int n_in,
                              void* d_out, int out_size, void* d_ws, size_t ws_size,
                              hipStream_t stream) {
  const float* query = (const float*)d_in[0];
  const float* keys  = (const float*)d_in[1];
  const int*   klen  = (const int*)d_in[2];
  const float* W1 = (const float*)d_in[3];
  const float* b1 = (const float*)d_in[4];
  const float* W2 = (const float*)d_in[5];
  const float* b2 = (const float*)d_in[6];
  const float* Wd = (const float*)d_in[7];
  const float* bd = (const float*)d_in[8];
  float* out = (float*)d_out;

  const int B = in_sizes[2];  // 4096
  hipLaunchKernelGGL(din_kernel, dim3(B), dim3(256), 0, stream,
                     query, keys, klen, W1, b1, W2, b2, Wd, bd, out);
}